// Round 22
// baseline (87.475 us; speedup 1.0000x reference)
//
#include <hip/hip_runtime.h>
#include <hip/hip_fp16.h>

#define G_ 20000
#define W_ 8
#define K_ 16
#define T_ 1500
#define B_ 256
#define D_ 2

using h4  = __attribute__((ext_vector_type(4))) __fp16;
using f4v = __attribute__((ext_vector_type(4))) float;
typedef decltype(__builtin_amdgcn_cvt_pkrtz(0.0f, 0.0f)) v2h;  // __fp16 x2

// ---------- prep: feat (B,T) -> featT (T,B) ----------
__global__ void transpose_feat(const float* __restrict__ feat,
                               float* __restrict__ featT) {
    __shared__ float tile[32][33];
    int t0 = blockIdx.x * 32;
    int b0 = blockIdx.y * 32;
    int tx = threadIdx.x, ty = threadIdx.y;  // block (32,8)
    #pragma unroll
    for (int i = 0; i < 32; i += 8) {
        int bb = b0 + ty + i, tt = t0 + tx;
        if (tt < T_) tile[ty + i][tx] = feat[bb * T_ + tt];
    }
    __syncthreads();
    #pragma unroll
    for (int i = 0; i < 32; i += 8) {
        int tt = t0 + ty + i, bb = b0 + tx;
        if (tt < T_) featT[tt * B_ + bb] = tile[tx][ty + i];
    }
}

// ---------- main MFMA kernel ----------

__device__ __forceinline__ unsigned cvtpk_u(float a, float b) {
    v2h t = __builtin_amdgcn_cvt_pkrtz(a, b);
    unsigned u; __builtin_memcpy(&u, &t, 4);
    return u;
}
__device__ __forceinline__ unsigned u_from_v2h(v2h h) {
    unsigned u; __builtin_memcpy(&u, &h, 4); return u;
}

// SELU on a 4-f32 mfma accumulator quad -> packed f16 pair (next B frag).
// exp2 in f32; affine/min/max tail in packed f16 (v_pk_*). 12 inst/quad.
__device__ __forceinline__ uint2 selu_quad(f4v acc) {
    const v2h A2  = {(__fp16)( 1.6732632423543772f), (__fp16)( 1.6732632423543772f)};
    const v2h nA2 = {(__fp16)(-1.6732632423543772f), (__fp16)(-1.6732632423543772f)};
    const v2h L2h = {(__fp16)( 0.6931471805599453f), (__fp16)( 0.6931471805599453f)};
    const v2h Z2  = {(__fp16)0.0f, (__fp16)0.0f};
    float e0 = __builtin_amdgcn_exp2f(acc[0]);
    float e1 = __builtin_amdgcn_exp2f(acc[1]);
    float e2 = __builtin_amdgcn_exp2f(acc[2]);
    float e3 = __builtin_amdgcn_exp2f(acc[3]);
    v2h hu01 = __builtin_amdgcn_cvt_pkrtz(acc[0], acc[1]);
    v2h hu23 = __builtin_amdgcn_cvt_pkrtz(acc[2], acc[3]);
    v2h he01 = __builtin_amdgcn_cvt_pkrtz(e0, e1);
    v2h he23 = __builtin_amdgcn_cvt_pkrtz(e2, e3);
    v2h m01 = __builtin_elementwise_min(he01 * A2 + nA2, Z2);
    v2h m23 = __builtin_elementwise_min(he23 * A2 + nA2, Z2);
    v2h r01 = __builtin_elementwise_max(hu01, Z2) * L2h + m01;
    v2h r23 = __builtin_elementwise_max(hu23, Z2) * L2h + m23;
    return make_uint2(u_from_v2h(r01), u_from_v2h(r23));
}

__device__ __forceinline__ f4v mfma16(uint2 a, uint2 b, f4v c) {
    h4 ah, bh;
    __builtin_memcpy(&ah, &a, 8);
    __builtin_memcpy(&bh, &b, 8);
    return __builtin_amdgcn_mfma_f32_16x16x16f16(ah, bh, c, 0, 0, 0);
}

// Grid (B/128, G/16) = (2,1250) = 2500 blocks; block = 512 threads = 8
// waves; wave = 1 group-pair x 8 batch-tiles (128 rows).
// r22 change (single knob): __launch_bounds__(512,4) -> (512,8).
// Cross-round matrix: r16 = high occupancy (71%) + SERIAL chains -> 50us;
// r17-r21 = chain ILP + 2 blocks/CU cap (16 waves/CU) -> 43-46us. This is
// the untried cell: r21's kernel uses 52 VGPR which FITS the 64-VGPR cap
// of (512,8) => 4 blocks/CU = 32 waves/CU ceiling with unchanged codegen
// (cap > usage). Per-wave busy ~11% -> doubling resident waves attacks
// the 56% stall fraction directly.
__global__ __launch_bounds__(512, 8) void decoder_mfma(
    const float* __restrict__ featT,    // (T,B)
    const int*   __restrict__ tf_idx,   // (G,K)
    const float* __restrict__ W1,       // (G,W,K)
    const float* __restrict__ b1,       // (G,W)
    const float* __restrict__ Wm,       // (D,G,W,W)
    const float* __restrict__ bm,       // (D,G,W)
    const float* __restrict__ Wf,       // (G,W)
    const float* __restrict__ bf,       // (G,)
    float* __restrict__ out)            // (B,G)
{
    const float LOG2E = 1.44269504088896340736f;
    const float SCALE = 1.0507009873554805f;
    const float SL    = SCALE * LOG2E;

    const int tid  = threadIdx.x;
    const int lane = tid & 63;
    const int wv   = tid >> 6;              // 0..7 = pair within chunk
    const int bh   = blockIdx.x;             // batch half (128 rows)
    const int gc   = blockIdx.y;             // group-chunk of 16
    const char* fc = (const char*)featT;

    const int col   = lane & 15;             // A-row / B-col / C-col
    const int q     = lane >> 4;             // k/row quad
    const bool rlt8 = col < 8;
    const int kq    = (q & 1) * 4;           // k-offset within an 8-wide row

    __shared__ float smem[128][17];

    {
        const int pp = wv;
        const int p  = gc * 8 + pp;
        const int g0 = 2 * p, g1 = 2 * p + 1;
        const int ga = rlt8 ? g0 : g1;       // row-side group (A-row = col)
        const int ra = rlt8 ? col : col - 8;
        const int gq = (q < 2) ? g0 : g1;    // row-quad-side group (C rows)

        // --- gather bases: 8 addrs once; t-steps are imm offsets ---
        int4 id0 = *(const int4*)(tf_idx + g0 * K_ + 4 * q);
        int4 id1 = *(const int4*)(tf_idx + g1 * K_ + 4 * q);
        const unsigned vb0 = (unsigned)((bh * 128 + col) * 4);
        const char* p0 = fc + (((unsigned)id0.x << 10) + vb0);
        const char* p1 = fc + (((unsigned)id0.y << 10) + vb0);
        const char* p2 = fc + (((unsigned)id0.z << 10) + vb0);
        const char* p3 = fc + (((unsigned)id0.w << 10) + vb0);
        const char* p4 = fc + (((unsigned)id1.x << 10) + vb0);
        const char* p5 = fc + (((unsigned)id1.y << 10) + vb0);
        const char* p6 = fc + (((unsigned)id1.z << 10) + vb0);
        const char* p7 = fc + (((unsigned)id1.w << 10) + vb0);

        // --- hoisted gathers: 8 tiles x 8 values, deep ILP ---
        float xv[8][8];
        #pragma unroll
        for (int t = 0; t < 8; ++t) {
            xv[t][0] = *(const float*)(p0 + t * 64);
            xv[t][1] = *(const float*)(p1 + t * 64);
            xv[t][2] = *(const float*)(p2 + t * 64);
            xv[t][3] = *(const float*)(p3 + t * 64);
            xv[t][4] = *(const float*)(p4 + t * 64);
            xv[t][5] = *(const float*)(p5 + t * 64);
            xv[t][6] = *(const float*)(p6 + t * 64);
            xv[t][7] = *(const float*)(p7 + t * 64);
        }

        // --- A1: rows0-7 = LOG2E*W1_g0[w][k], rows8-15 = g1; split halves ---
        float4 w1v = *(const float4*)(W1 + ((long)ga * W_ + ra) * K_ + 4 * q);
        uint2 af;
        af.x = cvtpk_u(LOG2E * w1v.x, LOG2E * w1v.y);
        af.y = cvtpk_u(LOG2E * w1v.z, LOG2E * w1v.w);
        uint2 A1g0, A1g1;
        A1g0.x = rlt8 ? af.x : 0u;  A1g0.y = rlt8 ? af.y : 0u;
        A1g1.x = rlt8 ? 0u : af.x;  A1g1.y = rlt8 ? 0u : af.y;

        // --- AM0/AM1 block-diag: nonzero iff (col<8)==(q<2) ---
        const bool diag = (rlt8 == (q < 2));
        float4 wm0v = *(const float4*)(Wm + ((long)0 * G_ + ga) * 64 + ra * 8 + kq);
        float4 wm1v = *(const float4*)(Wm + ((long)1 * G_ + ga) * 64 + ra * 8 + kq);
        uint2 AM0, AM1;
        AM0.x = diag ? cvtpk_u(SL * wm0v.x, SL * wm0v.y) : 0u;
        AM0.y = diag ? cvtpk_u(SL * wm0v.z, SL * wm0v.w) : 0u;
        AM1.x = diag ? cvtpk_u(SL * wm1v.x, SL * wm1v.y) : 0u;
        AM1.y = diag ? cvtpk_u(SL * wm1v.z, SL * wm1v.w) : 0u;

        // --- AF: row0 = SCALE*Wf_g0 (k0-7); row8 = SCALE*Wf_g1 (k8-15) ---
        const bool fnz = (ra == 0) && diag;
        float4 wfv = *(const float4*)(Wf + (long)ga * W_ + kq);
        uint2 AF;
        AF.x = fnz ? cvtpk_u(SCALE * wfv.x, SCALE * wfv.y) : 0u;
        AF.y = fnz ? cvtpk_u(SCALE * wfv.z, SCALE * wfv.w) : 0u;

        // --- bias C-in frags (rows 4q..4q+3) ---
        float4 b1v  = *(const float4*)(b1 + (long)gq * W_ + kq);
        float4 bm0v = *(const float4*)(bm + ((long)0 * G_ + gq) * W_ + kq);
        float4 bm1v = *(const float4*)(bm + ((long)1 * G_ + gq) * W_ + kq);
        f4v bias1 = {LOG2E * b1v.x,  LOG2E * b1v.y,  LOG2E * b1v.z,  LOG2E * b1v.w};
        f4v bmf0  = {LOG2E * bm0v.x, LOG2E * bm0v.y, LOG2E * bm0v.z, LOG2E * bm0v.w};
        f4v bmf1  = {LOG2E * bm1v.x, LOG2E * bm1v.y, LOG2E * bm1v.z, LOG2E * bm1v.w};
        f4v bfin  = {0.f, 0.f, 0.f, 0.f};
        bfin[0] = ((q & 1) == 0) ? bf[gq] : 0.0f;   // rows 0 (g0) and 8 (g1)

        // --- 8 register-disjoint chains: compiler interleaves for ILP ---
        #pragma unroll
        for (int t = 0; t < 8; ++t) {
            uint2 bg0, bg1;
            bg0.x = cvtpk_u(xv[t][0], xv[t][1]); bg0.y = cvtpk_u(xv[t][2], xv[t][3]);
            bg1.x = cvtpk_u(xv[t][4], xv[t][5]); bg1.y = cvtpk_u(xv[t][6], xv[t][7]);

            f4v acc = mfma16(A1g0, bg0, bias1);
            acc     = mfma16(A1g1, bg1, acc);

            uint2 bh2 = selu_quad(acc);
            acc = mfma16(AM0, bh2, bmf0);
            bh2 = selu_quad(acc);
            acc = mfma16(AM1, bh2, bmf1);
            bh2 = selu_quad(acc);
            acc = mfma16(AF, bh2, bfin);

            // D row0 (g even) in lanes q==0, row8 (g odd) in q==2
            if (!(q & 1))
                smem[t * 16 + col][2 * pp + ((q >> 1) & 1)] = acc[0];
        }
    }

    __syncthreads();

    // epilogue: 4 threads per batch row (float4 each) -> full 64B lines
    {
        const int row = tid >> 2;           // 0..127 (local batch row)
        const int seg = tid & 3;            // 16B segment within the line
        float4 v = make_float4(smem[row][seg * 4 + 0], smem[row][seg * 4 + 1],
                               smem[row][seg * 4 + 2], smem[row][seg * 4 + 3]);
        *(float4*)(out + (long)(bh * 128 + row) * G_ + gc * 16 + seg * 4) = v;
    }
}

// ---------- fallback (no workspace): direct scalar path ----------
#define FGPB 4
__device__ __forceinline__ float selu_f(float x) {
    const float scale = 1.0507009873554805f;
    const float sa    = 1.7580993408473766f;
    float e   = __expf(x);
    float neg = fmaf(sa, e, -sa);
    return x > 0.0f ? scale * x : neg;
}
template<bool TRANSPOSED>
__global__ __launch_bounds__(256) void decoder_kernel(
    const float* __restrict__ featsrc, const int* __restrict__ tf_idx,
    const float* __restrict__ W1, const float* __restrict__ b1,
    const float* __restrict__ Wm, const float* __restrict__ bm,
    const float* __restrict__ Wf, const float* __restrict__ bf,
    float* __restrict__ out)
{
    const int b  = threadIdx.x;
    const int g0 = blockIdx.x * FGPB;
    float res[FGPB];
    #pragma unroll
    for (int gi = 0; gi < FGPB; ++gi) {
        const int g = g0 + gi;
        float xg[K_];
        #pragma unroll
        for (int k = 0; k < K_; ++k) {
            int t = tf_idx[g * K_ + k];
            xg[k] = TRANSPOSED ? featsrc[t * B_ + b] : featsrc[b * T_ + t];
        }
        float h[W_];
        #pragma unroll
        for (int w = 0; w < W_; ++w) {
            float acc = b1[g * W_ + w];
            #pragma unroll
            for (int k = 0; k < K_; ++k)
                acc = fmaf(xg[k], W1[(g * W_ + w) * K_ + k], acc);
            h[w] = selu_f(acc);
        }
        #pragma unroll
        for (int d = 0; d < D_; ++d) {
            const float* wmd = Wm + ((size_t)d * G_ + g) * (W_ * W_);
            const float* bmd = bm + ((size_t)d * G_ + g) * W_;
            float h2[W_];
            #pragma unroll
            for (int v = 0; v < W_; ++v) {
                float acc = bmd[v];
                #pragma unroll
                for (int w = 0; w < W_; ++w)
                    acc = fmaf(h[w], wmd[v * W_ + w], acc);
                h2[v] = selu_f(acc);
            }
            #pragma unroll
            for (int w = 0; w < W_; ++w) h[w] = h2[w];
        }
        float acc = bf[g];
        #pragma unroll
        for (int w = 0; w < W_; ++w)
            acc = fmaf(h[w], Wf[g * W_ + w], acc);
        res[gi] = acc;
    }
    float4* o = (float4*)(out + (size_t)b * G_ + g0);
    o[0] = make_float4(res[0], res[1], res[2], res[3]);
}

extern "C" void kernel_launch(void* const* d_in, const int* in_sizes, int n_in,
                              void* d_out, int out_size, void* d_ws, size_t ws_size,
                              hipStream_t stream) {
    const float* feat   = (const float*)d_in[0];
    const int*   tf_idx = (const int*)  d_in[1];
    const float* W1     = (const float*)d_in[2];
    const float* b1     = (const float*)d_in[3];
    const float* Wm     = (const float*)d_in[4];
    const float* bm     = (const float*)d_in[5];
    const float* Wf     = (const float*)d_in[6];
    const float* bf     = (const float*)d_in[7];
    float* out = (float*)d_out;

    const size_t featT_b = (size_t)T_ * B_ * sizeof(float);   // 1.536 MB

    if (ws_size >= featT_b) {
        float* featT = (float*)d_ws;
        hipLaunchKernelGGL(transpose_feat, dim3((T_ + 31) / 32, B_ / 32),
                           dim3(32, 8), 0, stream, feat, featT);
        hipLaunchKernelGGL(decoder_mfma, dim3(B_ / 128, G_ / 16), dim3(512), 0,
                           stream, featT, tf_idx, W1, b1, Wm, bm, Wf, bf, out);
    } else {
        hipLaunchKernelGGL((decoder_kernel<false>), dim3(G_ / FGPB), dim3(B_), 0,
                           stream, feat, tf_idx, W1, b1, Wm, bm, Wf, bf, out);
    }
}

// Round 23
// 67.124 us; speedup vs baseline: 1.3032x; 1.3032x over previous
//
#include <hip/hip_runtime.h>
#include <hip/hip_fp16.h>

#define G_ 20000
#define W_ 8
#define K_ 16
#define T_ 1500
#define B_ 256
#define D_ 2

using h4  = __attribute__((ext_vector_type(4))) __fp16;
using f4v = __attribute__((ext_vector_type(4))) float;
typedef decltype(__builtin_amdgcn_cvt_pkrtz(0.0f, 0.0f)) v2h;  // __fp16 x2

// ---------- prep: feat (B,T) -> featT (T,B) ----------
__global__ void transpose_feat(const float* __restrict__ feat,
                               float* __restrict__ featT) {
    __shared__ float tile[32][33];
    int t0 = blockIdx.x * 32;
    int b0 = blockIdx.y * 32;
    int tx = threadIdx.x, ty = threadIdx.y;  // block (32,8)
    #pragma unroll
    for (int i = 0; i < 32; i += 8) {
        int bb = b0 + ty + i, tt = t0 + tx;
        if (tt < T_) tile[ty + i][tx] = feat[bb * T_ + tt];
    }
    __syncthreads();
    #pragma unroll
    for (int i = 0; i < 32; i += 8) {
        int tt = t0 + ty + i, bb = b0 + tx;
        if (tt < T_) featT[tt * B_ + bb] = tile[tx][ty + i];
    }
}

// ---------- main MFMA kernel ----------

__device__ __forceinline__ unsigned cvtpk_u(float a, float b) {
    v2h t = __builtin_amdgcn_cvt_pkrtz(a, b);
    unsigned u; __builtin_memcpy(&u, &t, 4);
    return u;
}
__device__ __forceinline__ unsigned u_from_v2h(v2h h) {
    unsigned u; __builtin_memcpy(&u, &h, 4); return u;
}

// SELU on a 4-f32 mfma accumulator quad -> packed f16 pair (next B frag).
// exp2 in f32; affine/min/max tail in packed f16 (v_pk_*). 12 inst/quad.
__device__ __forceinline__ uint2 selu_quad(f4v acc) {
    const v2h A2  = {(__fp16)( 1.6732632423543772f), (__fp16)( 1.6732632423543772f)};
    const v2h nA2 = {(__fp16)(-1.6732632423543772f), (__fp16)(-1.6732632423543772f)};
    const v2h L2h = {(__fp16)( 0.6931471805599453f), (__fp16)( 0.6931471805599453f)};
    const v2h Z2  = {(__fp16)0.0f, (__fp16)0.0f};
    float e0 = __builtin_amdgcn_exp2f(acc[0]);
    float e1 = __builtin_amdgcn_exp2f(acc[1]);
    float e2 = __builtin_amdgcn_exp2f(acc[2]);
    float e3 = __builtin_amdgcn_exp2f(acc[3]);
    v2h hu01 = __builtin_amdgcn_cvt_pkrtz(acc[0], acc[1]);
    v2h hu23 = __builtin_amdgcn_cvt_pkrtz(acc[2], acc[3]);
    v2h he01 = __builtin_amdgcn_cvt_pkrtz(e0, e1);
    v2h he23 = __builtin_amdgcn_cvt_pkrtz(e2, e3);
    v2h m01 = __builtin_elementwise_min(he01 * A2 + nA2, Z2);
    v2h m23 = __builtin_elementwise_min(he23 * A2 + nA2, Z2);
    v2h r01 = __builtin_elementwise_max(hu01, Z2) * L2h + m01;
    v2h r23 = __builtin_elementwise_max(hu23, Z2) * L2h + m23;
    return make_uint2(u_from_v2h(r01), u_from_v2h(r23));
}

__device__ __forceinline__ f4v mfma16(uint2 a, uint2 b, f4v c) {
    h4 ah, bh;
    __builtin_memcpy(&ah, &a, 8);
    __builtin_memcpy(&bh, &b, 8);
    return __builtin_amdgcn_mfma_f32_16x16x16f16(ah, bh, c, 0, 0, 0);
}

// Grid (B/128, G/16) = (2,1250) = 2500 blocks; block = 512 threads = 8
// waves; wave = 1 group-pair x 8 batch-tiles (128 rows).
// r22 post-mortem: (512,8)'s 64-VGPR cap SPILLED the xv[8][8] hoist
// (VGPR 52->32, scratch traffic 200MB, 2x regression). The allocator
// compiles TO the cap — caps <= 64 are poison for this kernel.
// r23: revert to the r21 kernel verbatim, knob (512,4) -> (512,6):
// VGPR cap 85 > 52 used (codegen preserved), residency 2 -> 3 blocks/CU
// (24 waves/CU, 75% ceiling). The untried {8-chain ILP} x {3 blocks/CU}
// cell. Guard: if counters show VGPR < ~45, the cap squeezed -> closed.
__global__ __launch_bounds__(512, 6) void decoder_mfma(
    const float* __restrict__ featT,    // (T,B)
    const int*   __restrict__ tf_idx,   // (G,K)
    const float* __restrict__ W1,       // (G,W,K)
    const float* __restrict__ b1,       // (G,W)
    const float* __restrict__ Wm,       // (D,G,W,W)
    const float* __restrict__ bm,       // (D,G,W)
    const float* __restrict__ Wf,       // (G,W)
    const float* __restrict__ bf,       // (G,)
    float* __restrict__ out)            // (B,G)
{
    const float LOG2E = 1.44269504088896340736f;
    const float SCALE = 1.0507009873554805f;
    const float SL    = SCALE * LOG2E;

    const int tid  = threadIdx.x;
    const int lane = tid & 63;
    const int wv   = tid >> 6;              // 0..7 = pair within chunk
    const int bh   = blockIdx.x;             // batch half (128 rows)
    const int gc   = blockIdx.y;             // group-chunk of 16
    const char* fc = (const char*)featT;

    const int col   = lane & 15;             // A-row / B-col / C-col
    const int q     = lane >> 4;             // k/row quad
    const bool rlt8 = col < 8;
    const int kq    = (q & 1) * 4;           // k-offset within an 8-wide row

    __shared__ float smem[128][17];

    {
        const int pp = wv;
        const int p  = gc * 8 + pp;
        const int g0 = 2 * p, g1 = 2 * p + 1;
        const int ga = rlt8 ? g0 : g1;       // row-side group (A-row = col)
        const int ra = rlt8 ? col : col - 8;
        const int gq = (q < 2) ? g0 : g1;    // row-quad-side group (C rows)

        // --- gather bases: 8 addrs once; t-steps are imm offsets ---
        int4 id0 = *(const int4*)(tf_idx + g0 * K_ + 4 * q);
        int4 id1 = *(const int4*)(tf_idx + g1 * K_ + 4 * q);
        const unsigned vb0 = (unsigned)((bh * 128 + col) * 4);
        const char* p0 = fc + (((unsigned)id0.x << 10) + vb0);
        const char* p1 = fc + (((unsigned)id0.y << 10) + vb0);
        const char* p2 = fc + (((unsigned)id0.z << 10) + vb0);
        const char* p3 = fc + (((unsigned)id0.w << 10) + vb0);
        const char* p4 = fc + (((unsigned)id1.x << 10) + vb0);
        const char* p5 = fc + (((unsigned)id1.y << 10) + vb0);
        const char* p6 = fc + (((unsigned)id1.z << 10) + vb0);
        const char* p7 = fc + (((unsigned)id1.w << 10) + vb0);

        // --- hoisted gathers: 8 tiles x 8 values, deep ILP ---
        float xv[8][8];
        #pragma unroll
        for (int t = 0; t < 8; ++t) {
            xv[t][0] = *(const float*)(p0 + t * 64);
            xv[t][1] = *(const float*)(p1 + t * 64);
            xv[t][2] = *(const float*)(p2 + t * 64);
            xv[t][3] = *(const float*)(p3 + t * 64);
            xv[t][4] = *(const float*)(p4 + t * 64);
            xv[t][5] = *(const float*)(p5 + t * 64);
            xv[t][6] = *(const float*)(p6 + t * 64);
            xv[t][7] = *(const float*)(p7 + t * 64);
        }

        // --- A1: rows0-7 = LOG2E*W1_g0[w][k], rows8-15 = g1; split halves ---
        float4 w1v = *(const float4*)(W1 + ((long)ga * W_ + ra) * K_ + 4 * q);
        uint2 af;
        af.x = cvtpk_u(LOG2E * w1v.x, LOG2E * w1v.y);
        af.y = cvtpk_u(LOG2E * w1v.z, LOG2E * w1v.w);
        uint2 A1g0, A1g1;
        A1g0.x = rlt8 ? af.x : 0u;  A1g0.y = rlt8 ? af.y : 0u;
        A1g1.x = rlt8 ? 0u : af.x;  A1g1.y = rlt8 ? 0u : af.y;

        // --- AM0/AM1 block-diag: nonzero iff (col<8)==(q<2) ---
        const bool diag = (rlt8 == (q < 2));
        float4 wm0v = *(const float4*)(Wm + ((long)0 * G_ + ga) * 64 + ra * 8 + kq);
        float4 wm1v = *(const float4*)(Wm + ((long)1 * G_ + ga) * 64 + ra * 8 + kq);
        uint2 AM0, AM1;
        AM0.x = diag ? cvtpk_u(SL * wm0v.x, SL * wm0v.y) : 0u;
        AM0.y = diag ? cvtpk_u(SL * wm0v.z, SL * wm0v.w) : 0u;
        AM1.x = diag ? cvtpk_u(SL * wm1v.x, SL * wm1v.y) : 0u;
        AM1.y = diag ? cvtpk_u(SL * wm1v.z, SL * wm1v.w) : 0u;

        // --- AF: row0 = SCALE*Wf_g0 (k0-7); row8 = SCALE*Wf_g1 (k8-15) ---
        const bool fnz = (ra == 0) && diag;
        float4 wfv = *(const float4*)(Wf + (long)ga * W_ + kq);
        uint2 AF;
        AF.x = fnz ? cvtpk_u(SCALE * wfv.x, SCALE * wfv.y) : 0u;
        AF.y = fnz ? cvtpk_u(SCALE * wfv.z, SCALE * wfv.w) : 0u;

        // --- bias C-in frags (rows 4q..4q+3) ---
        float4 b1v  = *(const float4*)(b1 + (long)gq * W_ + kq);
        float4 bm0v = *(const float4*)(bm + ((long)0 * G_ + gq) * W_ + kq);
        float4 bm1v = *(const float4*)(bm + ((long)1 * G_ + gq) * W_ + kq);
        f4v bias1 = {LOG2E * b1v.x,  LOG2E * b1v.y,  LOG2E * b1v.z,  LOG2E * b1v.w};
        f4v bmf0  = {LOG2E * bm0v.x, LOG2E * bm0v.y, LOG2E * bm0v.z, LOG2E * bm0v.w};
        f4v bmf1  = {LOG2E * bm1v.x, LOG2E * bm1v.y, LOG2E * bm1v.z, LOG2E * bm1v.w};
        f4v bfin  = {0.f, 0.f, 0.f, 0.f};
        bfin[0] = ((q & 1) == 0) ? bf[gq] : 0.0f;   // rows 0 (g0) and 8 (g1)

        // --- 8 register-disjoint chains: compiler interleaves for ILP ---
        #pragma unroll
        for (int t = 0; t < 8; ++t) {
            uint2 bg0, bg1;
            bg0.x = cvtpk_u(xv[t][0], xv[t][1]); bg0.y = cvtpk_u(xv[t][2], xv[t][3]);
            bg1.x = cvtpk_u(xv[t][4], xv[t][5]); bg1.y = cvtpk_u(xv[t][6], xv[t][7]);

            f4v acc = mfma16(A1g0, bg0, bias1);
            acc     = mfma16(A1g1, bg1, acc);

            uint2 bh2 = selu_quad(acc);
            acc = mfma16(AM0, bh2, bmf0);
            bh2 = selu_quad(acc);
            acc = mfma16(AM1, bh2, bmf1);
            bh2 = selu_quad(acc);
            acc = mfma16(AF, bh2, bfin);

            // D row0 (g even) in lanes q==0, row8 (g odd) in q==2
            if (!(q & 1))
                smem[t * 16 + col][2 * pp + ((q >> 1) & 1)] = acc[0];
        }
    }

    __syncthreads();

    // epilogue: 4 threads per batch row (float4 each) -> full 64B lines
    {
        const int row = tid >> 2;           // 0..127 (local batch row)
        const int seg = tid & 3;            // 16B segment within the line
        float4 v = make_float4(smem[row][seg * 4 + 0], smem[row][seg * 4 + 1],
                               smem[row][seg * 4 + 2], smem[row][seg * 4 + 3]);
        *(float4*)(out + (long)(bh * 128 + row) * G_ + gc * 16 + seg * 4) = v;
    }
}

// ---------- fallback (no workspace): direct scalar path ----------
#define FGPB 4
__device__ __forceinline__ float selu_f(float x) {
    const float scale = 1.0507009873554805f;
    const float sa    = 1.7580993408473766f;
    float e   = __expf(x);
    float neg = fmaf(sa, e, -sa);
    return x > 0.0f ? scale * x : neg;
}
template<bool TRANSPOSED>
__global__ __launch_bounds__(256) void decoder_kernel(
    const float* __restrict__ featsrc, const int* __restrict__ tf_idx,
    const float* __restrict__ W1, const float* __restrict__ b1,
    const float* __restrict__ Wm, const float* __restrict__ bm,
    const float* __restrict__ Wf, const float* __restrict__ bf,
    float* __restrict__ out)
{
    const int b  = threadIdx.x;
    const int g0 = blockIdx.x * FGPB;
    float res[FGPB];
    #pragma unroll
    for (int gi = 0; gi < FGPB; ++gi) {
        const int g = g0 + gi;
        float xg[K_];
        #pragma unroll
        for (int k = 0; k < K_; ++k) {
            int t = tf_idx[g * K_ + k];
            xg[k] = TRANSPOSED ? featsrc[t * B_ + b] : featsrc[b * T_ + t];
        }
        float h[W_];
        #pragma unroll
        for (int w = 0; w < W_; ++w) {
            float acc = b1[g * W_ + w];
            #pragma unroll
            for (int k = 0; k < K_; ++k)
                acc = fmaf(xg[k], W1[(g * W_ + w) * K_ + k], acc);
            h[w] = selu_f(acc);
        }
        #pragma unroll
        for (int d = 0; d < D_; ++d) {
            const float* wmd = Wm + ((size_t)d * G_ + g) * (W_ * W_);
            const float* bmd = bm + ((size_t)d * G_ + g) * W_;
            float h2[W_];
            #pragma unroll
            for (int v = 0; v < W_; ++v) {
                float acc = bmd[v];
                #pragma unroll
                for (int w = 0; w < W_; ++w)
                    acc = fmaf(h[w], wmd[v * W_ + w], acc);
                h2[v] = selu_f(acc);
            }
            #pragma unroll
            for (int w = 0; w < W_; ++w) h[w] = h2[w];
        }
        float acc = bf[g];
        #pragma unroll
        for (int w = 0; w < W_; ++w)
            acc = fmaf(h[w], Wf[g * W_ + w], acc);
        res[gi] = acc;
    }
    float4* o = (float4*)(out + (size_t)b * G_ + g0);
    o[0] = make_float4(res[0], res[1], res[2], res[3]);
}

extern "C" void kernel_launch(void* const* d_in, const int* in_sizes, int n_in,
                              void* d_out, int out_size, void* d_ws, size_t ws_size,
                              hipStream_t stream) {
    const float* feat   = (const float*)d_in[0];
    const int*   tf_idx = (const int*)  d_in[1];
    const float* W1     = (const float*)d_in[2];
    const float* b1     = (const float*)d_in[3];
    const float* Wm     = (const float*)d_in[4];
    const float* bm     = (const float*)d_in[5];
    const float* Wf     = (const float*)d_in[6];
    const float* bf     = (const float*)d_in[7];
    float* out = (float*)d_out;

    const size_t featT_b = (size_t)T_ * B_ * sizeof(float);   // 1.536 MB

    if (ws_size >= featT_b) {
        float* featT = (float*)d_ws;
        hipLaunchKernelGGL(transpose_feat, dim3((T_ + 31) / 32, B_ / 32),
                           dim3(32, 8), 0, stream, feat, featT);
        hipLaunchKernelGGL(decoder_mfma, dim3(B_ / 128, G_ / 16), dim3(512), 0,
                           stream, featT, tf_idx, W1, b1, Wm, bm, Wf, bf, out);
    } else {
        hipLaunchKernelGGL((decoder_kernel<false>), dim3(G_ / FGPB), dim3(B_), 0,
                           stream, feat, tf_idx, W1, b1, Wm, bm, Wf, bf, out);
    }
}

// Round 24
// 44.528 us; speedup vs baseline: 1.9645x; 1.5074x over previous
//
#include <hip/hip_runtime.h>
#include <hip/hip_fp16.h>

#define G_ 20000
#define W_ 8
#define K_ 16
#define T_ 1500
#define B_ 256
#define D_ 2

using h4  = __attribute__((ext_vector_type(4))) __fp16;
using f4v = __attribute__((ext_vector_type(4))) float;
typedef decltype(__builtin_amdgcn_cvt_pkrtz(0.0f, 0.0f)) v2h;  // __fp16 x2

// ---------- prep: feat (B,T) -> featT (T,B) ----------
__global__ void transpose_feat(const float* __restrict__ feat,
                               float* __restrict__ featT) {
    __shared__ float tile[32][33];
    int t0 = blockIdx.x * 32;
    int b0 = blockIdx.y * 32;
    int tx = threadIdx.x, ty = threadIdx.y;  // block (32,8)
    #pragma unroll
    for (int i = 0; i < 32; i += 8) {
        int bb = b0 + ty + i, tt = t0 + tx;
        if (tt < T_) tile[ty + i][tx] = feat[bb * T_ + tt];
    }
    __syncthreads();
    #pragma unroll
    for (int i = 0; i < 32; i += 8) {
        int tt = t0 + ty + i, bb = b0 + tx;
        if (tt < T_) featT[tt * B_ + bb] = tile[tx][ty + i];
    }
}

// ---------- main MFMA kernel ----------

__device__ __forceinline__ unsigned cvtpk_u(float a, float b) {
    v2h t = __builtin_amdgcn_cvt_pkrtz(a, b);
    unsigned u; __builtin_memcpy(&u, &t, 4);
    return u;
}
__device__ __forceinline__ unsigned u_from_v2h(v2h h) {
    unsigned u; __builtin_memcpy(&u, &h, 4); return u;
}

// SELU on a 4-f32 mfma accumulator quad -> packed f16 pair (next B frag).
// exp2 in f32; affine/min/max tail in packed f16 (v_pk_*). 12 inst/quad.
__device__ __forceinline__ uint2 selu_quad(f4v acc) {
    const v2h A2  = {(__fp16)( 1.6732632423543772f), (__fp16)( 1.6732632423543772f)};
    const v2h nA2 = {(__fp16)(-1.6732632423543772f), (__fp16)(-1.6732632423543772f)};
    const v2h L2h = {(__fp16)( 0.6931471805599453f), (__fp16)( 0.6931471805599453f)};
    const v2h Z2  = {(__fp16)0.0f, (__fp16)0.0f};
    float e0 = __builtin_amdgcn_exp2f(acc[0]);
    float e1 = __builtin_amdgcn_exp2f(acc[1]);
    float e2 = __builtin_amdgcn_exp2f(acc[2]);
    float e3 = __builtin_amdgcn_exp2f(acc[3]);
    v2h hu01 = __builtin_amdgcn_cvt_pkrtz(acc[0], acc[1]);
    v2h hu23 = __builtin_amdgcn_cvt_pkrtz(acc[2], acc[3]);
    v2h he01 = __builtin_amdgcn_cvt_pkrtz(e0, e1);
    v2h he23 = __builtin_amdgcn_cvt_pkrtz(e2, e3);
    v2h m01 = __builtin_elementwise_min(he01 * A2 + nA2, Z2);
    v2h m23 = __builtin_elementwise_min(he23 * A2 + nA2, Z2);
    v2h r01 = __builtin_elementwise_max(hu01, Z2) * L2h + m01;
    v2h r23 = __builtin_elementwise_max(hu23, Z2) * L2h + m23;
    return make_uint2(u_from_v2h(r01), u_from_v2h(r23));
}

__device__ __forceinline__ f4v mfma16(uint2 a, uint2 b, f4v c) {
    h4 ah, bh;
    __builtin_memcpy(&ah, &a, 8);
    __builtin_memcpy(&bh, &b, 8);
    return __builtin_amdgcn_mfma_f32_16x16x16f16(ah, bh, c, 0, 0, 0);
}

// Grid (B/128, G/16) = (2,1250) = 2500 blocks; block = 512 threads = 8
// waves; wave = 1 group-pair x 8 batch-tiles (128 rows).
// r24 = EXACT revert to r21 (best known: 44.1us, 52 VGPR, no spill).
// Residency axis closed by measurement:
//   (512,4) 8-chain: 52 VGPR, 34% occ, ~43us  <- this config
//   (512,6) 8-chain: 40 VGPR SPILL, 72us (r23)
//   (512,8) 8-chain: 32 VGPR SPILL, 96us (r22)
//   (512,8) serial : 32 VGPR, 71% occ, ~50us (r16)
// The allocator re-allocates (and spills) under any cap tighter than
// (512,4)'s 128 — min-waves > 4 is poison for the xv[8][8] hoist.
__global__ __launch_bounds__(512, 4) void decoder_mfma(
    const float* __restrict__ featT,    // (T,B)
    const int*   __restrict__ tf_idx,   // (G,K)
    const float* __restrict__ W1,       // (G,W,K)
    const float* __restrict__ b1,       // (G,W)
    const float* __restrict__ Wm,       // (D,G,W,W)
    const float* __restrict__ bm,       // (D,G,W)
    const float* __restrict__ Wf,       // (G,W)
    const float* __restrict__ bf,       // (G,)
    float* __restrict__ out)            // (B,G)
{
    const float LOG2E = 1.44269504088896340736f;
    const float SCALE = 1.0507009873554805f;
    const float SL    = SCALE * LOG2E;

    const int tid  = threadIdx.x;
    const int lane = tid & 63;
    const int wv   = tid >> 6;              // 0..7 = pair within chunk
    const int bh   = blockIdx.x;             // batch half (128 rows)
    const int gc   = blockIdx.y;             // group-chunk of 16
    const char* fc = (const char*)featT;

    const int col   = lane & 15;             // A-row / B-col / C-col
    const int q     = lane >> 4;             // k/row quad
    const bool rlt8 = col < 8;
    const int kq    = (q & 1) * 4;           // k-offset within an 8-wide row

    __shared__ float smem[128][17];

    {
        const int pp = wv;
        const int p  = gc * 8 + pp;
        const int g0 = 2 * p, g1 = 2 * p + 1;
        const int ga = rlt8 ? g0 : g1;       // row-side group (A-row = col)
        const int ra = rlt8 ? col : col - 8;
        const int gq = (q < 2) ? g0 : g1;    // row-quad-side group (C rows)

        // --- gather bases: 8 addrs once; t-steps are imm offsets ---
        int4 id0 = *(const int4*)(tf_idx + g0 * K_ + 4 * q);
        int4 id1 = *(const int4*)(tf_idx + g1 * K_ + 4 * q);
        const unsigned vb0 = (unsigned)((bh * 128 + col) * 4);
        const char* p0 = fc + (((unsigned)id0.x << 10) + vb0);
        const char* p1 = fc + (((unsigned)id0.y << 10) + vb0);
        const char* p2 = fc + (((unsigned)id0.z << 10) + vb0);
        const char* p3 = fc + (((unsigned)id0.w << 10) + vb0);
        const char* p4 = fc + (((unsigned)id1.x << 10) + vb0);
        const char* p5 = fc + (((unsigned)id1.y << 10) + vb0);
        const char* p6 = fc + (((unsigned)id1.z << 10) + vb0);
        const char* p7 = fc + (((unsigned)id1.w << 10) + vb0);

        // --- hoisted gathers: 8 tiles x 8 values (64 VGPR), deep ILP ---
        float xv[8][8];
        #pragma unroll
        for (int t = 0; t < 8; ++t) {
            xv[t][0] = *(const float*)(p0 + t * 64);
            xv[t][1] = *(const float*)(p1 + t * 64);
            xv[t][2] = *(const float*)(p2 + t * 64);
            xv[t][3] = *(const float*)(p3 + t * 64);
            xv[t][4] = *(const float*)(p4 + t * 64);
            xv[t][5] = *(const float*)(p5 + t * 64);
            xv[t][6] = *(const float*)(p6 + t * 64);
            xv[t][7] = *(const float*)(p7 + t * 64);
        }

        // --- A1: rows0-7 = LOG2E*W1_g0[w][k], rows8-15 = g1; split halves ---
        float4 w1v = *(const float4*)(W1 + ((long)ga * W_ + ra) * K_ + 4 * q);
        uint2 af;
        af.x = cvtpk_u(LOG2E * w1v.x, LOG2E * w1v.y);
        af.y = cvtpk_u(LOG2E * w1v.z, LOG2E * w1v.w);
        uint2 A1g0, A1g1;
        A1g0.x = rlt8 ? af.x : 0u;  A1g0.y = rlt8 ? af.y : 0u;
        A1g1.x = rlt8 ? 0u : af.x;  A1g1.y = rlt8 ? 0u : af.y;

        // --- AM0/AM1 block-diag: nonzero iff (col<8)==(q<2) ---
        const bool diag = (rlt8 == (q < 2));
        float4 wm0v = *(const float4*)(Wm + ((long)0 * G_ + ga) * 64 + ra * 8 + kq);
        float4 wm1v = *(const float4*)(Wm + ((long)1 * G_ + ga) * 64 + ra * 8 + kq);
        uint2 AM0, AM1;
        AM0.x = diag ? cvtpk_u(SL * wm0v.x, SL * wm0v.y) : 0u;
        AM0.y = diag ? cvtpk_u(SL * wm0v.z, SL * wm0v.w) : 0u;
        AM1.x = diag ? cvtpk_u(SL * wm1v.x, SL * wm1v.y) : 0u;
        AM1.y = diag ? cvtpk_u(SL * wm1v.z, SL * wm1v.w) : 0u;

        // --- AF: row0 = SCALE*Wf_g0 (k0-7); row8 = SCALE*Wf_g1 (k8-15) ---
        const bool fnz = (ra == 0) && diag;
        float4 wfv = *(const float4*)(Wf + (long)ga * W_ + kq);
        uint2 AF;
        AF.x = fnz ? cvtpk_u(SCALE * wfv.x, SCALE * wfv.y) : 0u;
        AF.y = fnz ? cvtpk_u(SCALE * wfv.z, SCALE * wfv.w) : 0u;

        // --- bias C-in frags (rows 4q..4q+3) ---
        float4 b1v  = *(const float4*)(b1 + (long)gq * W_ + kq);
        float4 bm0v = *(const float4*)(bm + ((long)0 * G_ + gq) * W_ + kq);
        float4 bm1v = *(const float4*)(bm + ((long)1 * G_ + gq) * W_ + kq);
        f4v bias1 = {LOG2E * b1v.x,  LOG2E * b1v.y,  LOG2E * b1v.z,  LOG2E * b1v.w};
        f4v bmf0  = {LOG2E * bm0v.x, LOG2E * bm0v.y, LOG2E * bm0v.z, LOG2E * bm0v.w};
        f4v bmf1  = {LOG2E * bm1v.x, LOG2E * bm1v.y, LOG2E * bm1v.z, LOG2E * bm1v.w};
        f4v bfin  = {0.f, 0.f, 0.f, 0.f};
        bfin[0] = ((q & 1) == 0) ? bf[gq] : 0.0f;   // rows 0 (g0) and 8 (g1)

        // --- 8 register-disjoint chains: compiler interleaves for ILP ---
        #pragma unroll
        for (int t = 0; t < 8; ++t) {
            uint2 bg0, bg1;
            bg0.x = cvtpk_u(xv[t][0], xv[t][1]); bg0.y = cvtpk_u(xv[t][2], xv[t][3]);
            bg1.x = cvtpk_u(xv[t][4], xv[t][5]); bg1.y = cvtpk_u(xv[t][6], xv[t][7]);

            f4v acc = mfma16(A1g0, bg0, bias1);
            acc     = mfma16(A1g1, bg1, acc);

            uint2 bh2 = selu_quad(acc);
            acc = mfma16(AM0, bh2, bmf0);
            bh2 = selu_quad(acc);
            acc = mfma16(AM1, bh2, bmf1);
            bh2 = selu_quad(acc);
            acc = mfma16(AF, bh2, bfin);

            // D row0 (g even) in lanes q==0, row8 (g odd) in q==2
            if (!(q & 1))
                smem[t * 16 + col][2 * pp + ((q >> 1) & 1)] = acc[0];
        }
    }

    __syncthreads();

    // epilogue: 4 threads per batch row (float4 each) -> full 64B lines
    {
        const int row = tid >> 2;           // 0..127 (local batch row)
        const int seg = tid & 3;            // 16B segment within the line
        float4 v = make_float4(smem[row][seg * 4 + 0], smem[row][seg * 4 + 1],
                               smem[row][seg * 4 + 2], smem[row][seg * 4 + 3]);
        *(float4*)(out + (long)(bh * 128 + row) * G_ + gc * 16 + seg * 4) = v;
    }
}

// ---------- fallback (no workspace): direct scalar path ----------
#define FGPB 4
__device__ __forceinline__ float selu_f(float x) {
    const float scale = 1.0507009873554805f;
    const float sa    = 1.7580993408473766f;
    float e   = __expf(x);
    float neg = fmaf(sa, e, -sa);
    return x > 0.0f ? scale * x : neg;
}
template<bool TRANSPOSED>
__global__ __launch_bounds__(256) void decoder_kernel(
    const float* __restrict__ featsrc, const int* __restrict__ tf_idx,
    const float* __restrict__ W1, const float* __restrict__ b1,
    const float* __restrict__ Wm, const float* __restrict__ bm,
    const float* __restrict__ Wf, const float* __restrict__ bf,
    float* __restrict__ out)
{
    const int b  = threadIdx.x;
    const int g0 = blockIdx.x * FGPB;
    float res[FGPB];
    #pragma unroll
    for (int gi = 0; gi < FGPB; ++gi) {
        const int g = g0 + gi;
        float xg[K_];
        #pragma unroll
        for (int k = 0; k < K_; ++k) {
            int t = tf_idx[g * K_ + k];
            xg[k] = TRANSPOSED ? featsrc[t * B_ + b] : featsrc[b * T_ + t];
        }
        float h[W_];
        #pragma unroll
        for (int w = 0; w < W_; ++w) {
            float acc = b1[g * W_ + w];
            #pragma unroll
            for (int k = 0; k < K_; ++k)
                acc = fmaf(xg[k], W1[(g * W_ + w) * K_ + k], acc);
            h[w] = selu_f(acc);
        }
        #pragma unroll
        for (int d = 0; d < D_; ++d) {
            const float* wmd = Wm + ((size_t)d * G_ + g) * (W_ * W_);
            const float* bmd = bm + ((size_t)d * G_ + g) * W_;
            float h2[W_];
            #pragma unroll
            for (int v = 0; v < W_; ++v) {
                float acc = bmd[v];
                #pragma unroll
                for (int w = 0; w < W_; ++w)
                    acc = fmaf(h[w], wmd[v * W_ + w], acc);
                h2[v] = selu_f(acc);
            }
            #pragma unroll
            for (int w = 0; w < W_; ++w) h[w] = h2[w];
        }
        float acc = bf[g];
        #pragma unroll
        for (int w = 0; w < W_; ++w)
            acc = fmaf(h[w], Wf[g * W_ + w], acc);
        res[gi] = acc;
    }
    float4* o = (float4*)(out + (size_t)b * G_ + g0);
    o[0] = make_float4(res[0], res[1], res[2], res[3]);
}

extern "C" void kernel_launch(void* const* d_in, const int* in_sizes, int n_in,
                              void* d_out, int out_size, void* d_ws, size_t ws_size,
                              hipStream_t stream) {
    const float* feat   = (const float*)d_in[0];
    const int*   tf_idx = (const int*)  d_in[1];
    const float* W1     = (const float*)d_in[2];
    const float* b1     = (const float*)d_in[3];
    const float* Wm     = (const float*)d_in[4];
    const float* bm     = (const float*)d_in[5];
    const float* Wf     = (const float*)d_in[6];
    const float* bf     = (const float*)d_in[7];
    float* out = (float*)d_out;

    const size_t featT_b = (size_t)T_ * B_ * sizeof(float);   // 1.536 MB

    if (ws_size >= featT_b) {
        float* featT = (float*)d_ws;
        hipLaunchKernelGGL(transpose_feat, dim3((T_ + 31) / 32, B_ / 32),
                           dim3(32, 8), 0, stream, feat, featT);
        hipLaunchKernelGGL(decoder_mfma, dim3(B_ / 128, G_ / 16), dim3(512), 0,
                           stream, featT, tf_idx, W1, b1, Wm, bm, Wf, bf, out);
    } else {
        hipLaunchKernelGGL((decoder_kernel<false>), dim3(G_ / FGPB), dim3(B_), 0,
                           stream, feat, tf_idx, W1, b1, Wm, bm, Wf, bf, out);
    }
}

// Round 25
// 43.649 us; speedup vs baseline: 2.0040x; 1.0201x over previous
//
#include <hip/hip_runtime.h>
#include <hip/hip_fp16.h>

#define G_ 20000
#define W_ 8
#define K_ 16
#define T_ 1500
#define B_ 256
#define D_ 2

using h4  = __attribute__((ext_vector_type(4))) __fp16;
using f4v = __attribute__((ext_vector_type(4))) float;
typedef decltype(__builtin_amdgcn_cvt_pkrtz(0.0f, 0.0f)) v2h;  // __fp16 x2

// ---------- prep: feat (B,T) -> featT (T,B) ----------
__global__ void transpose_feat(const float* __restrict__ feat,
                               float* __restrict__ featT) {
    __shared__ float tile[32][33];
    int t0 = blockIdx.x * 32;
    int b0 = blockIdx.y * 32;
    int tx = threadIdx.x, ty = threadIdx.y;  // block (32,8)
    #pragma unroll
    for (int i = 0; i < 32; i += 8) {
        int bb = b0 + ty + i, tt = t0 + tx;
        if (tt < T_) tile[ty + i][tx] = feat[bb * T_ + tt];
    }
    __syncthreads();
    #pragma unroll
    for (int i = 0; i < 32; i += 8) {
        int tt = t0 + ty + i, bb = b0 + tx;
        if (tt < T_) featT[tt * B_ + bb] = tile[tx][ty + i];
    }
}

// ---------- main MFMA kernel ----------

__device__ __forceinline__ unsigned cvtpk_u(float a, float b) {
    v2h t = __builtin_amdgcn_cvt_pkrtz(a, b);
    unsigned u; __builtin_memcpy(&u, &t, 4);
    return u;
}
__device__ __forceinline__ unsigned u_from_v2h(v2h h) {
    unsigned u; __builtin_memcpy(&u, &h, 4); return u;
}

// SELU on a 4-f32 mfma accumulator quad -> packed f16 pair (next B frag).
// exp2 in f32; affine/min/max tail in packed f16 (v_pk_*). 12 inst/quad.
__device__ __forceinline__ uint2 selu_quad(f4v acc) {
    const v2h A2  = {(__fp16)( 1.6732632423543772f), (__fp16)( 1.6732632423543772f)};
    const v2h nA2 = {(__fp16)(-1.6732632423543772f), (__fp16)(-1.6732632423543772f)};
    const v2h L2h = {(__fp16)( 0.6931471805599453f), (__fp16)( 0.6931471805599453f)};
    const v2h Z2  = {(__fp16)0.0f, (__fp16)0.0f};
    float e0 = __builtin_amdgcn_exp2f(acc[0]);
    float e1 = __builtin_amdgcn_exp2f(acc[1]);
    float e2 = __builtin_amdgcn_exp2f(acc[2]);
    float e3 = __builtin_amdgcn_exp2f(acc[3]);
    v2h hu01 = __builtin_amdgcn_cvt_pkrtz(acc[0], acc[1]);
    v2h hu23 = __builtin_amdgcn_cvt_pkrtz(acc[2], acc[3]);
    v2h he01 = __builtin_amdgcn_cvt_pkrtz(e0, e1);
    v2h he23 = __builtin_amdgcn_cvt_pkrtz(e2, e3);
    v2h m01 = __builtin_elementwise_min(he01 * A2 + nA2, Z2);
    v2h m23 = __builtin_elementwise_min(he23 * A2 + nA2, Z2);
    v2h r01 = __builtin_elementwise_max(hu01, Z2) * L2h + m01;
    v2h r23 = __builtin_elementwise_max(hu23, Z2) * L2h + m23;
    return make_uint2(u_from_v2h(r01), u_from_v2h(r23));
}

__device__ __forceinline__ f4v mfma16(uint2 a, uint2 b, f4v c) {
    h4 ah, bh;
    __builtin_memcpy(&ah, &a, 8);
    __builtin_memcpy(&bh, &b, 8);
    return __builtin_amdgcn_mfma_f32_16x16x16f16(ah, bh, c, 0, 0, 0);
}

// Grid (B/128, G/16) = (2,1250) = 2500 blocks; block = 512 threads = 8
// waves; wave = 1 group-pair x 8 batch-tiles (128 rows).
// r25 change: MANUAL 2-WAY CHAIN INTERLEAVE. r24's plateau diagnosis:
// VALU 45% / MFMA 10% / HBM 13% — per-wave dependency stall dominates.
// Each chain is a strict ladder (5 mfma + 3 selu, ~190cy crit path);
// written sequentially the scheduler may not interleave across the ~80-
// inst chain bodies. Pair chains t,t+1 with statements alternated so
// every mfma/selu has an adjacent independent twin. +~14 VGPR (est ~66),
// far under (512,4)'s 128 cap (r22/r23: caps <=85 spill -> avoided).
__global__ __launch_bounds__(512, 4) void decoder_mfma(
    const float* __restrict__ featT,    // (T,B)
    const int*   __restrict__ tf_idx,   // (G,K)
    const float* __restrict__ W1,       // (G,W,K)
    const float* __restrict__ b1,       // (G,W)
    const float* __restrict__ Wm,       // (D,G,W,W)
    const float* __restrict__ bm,       // (D,G,W)
    const float* __restrict__ Wf,       // (G,W)
    const float* __restrict__ bf,       // (G,)
    float* __restrict__ out)            // (B,G)
{
    const float LOG2E = 1.44269504088896340736f;
    const float SCALE = 1.0507009873554805f;
    const float SL    = SCALE * LOG2E;

    const int tid  = threadIdx.x;
    const int lane = tid & 63;
    const int wv   = tid >> 6;              // 0..7 = pair within chunk
    const int bh   = blockIdx.x;             // batch half (128 rows)
    const int gc   = blockIdx.y;             // group-chunk of 16
    const char* fc = (const char*)featT;

    const int col   = lane & 15;             // A-row / B-col / C-col
    const int q     = lane >> 4;             // k/row quad
    const bool rlt8 = col < 8;
    const int kq    = (q & 1) * 4;           // k-offset within an 8-wide row

    __shared__ float smem[128][17];

    {
        const int pp = wv;
        const int p  = gc * 8 + pp;
        const int g0 = 2 * p, g1 = 2 * p + 1;
        const int ga = rlt8 ? g0 : g1;       // row-side group (A-row = col)
        const int ra = rlt8 ? col : col - 8;
        const int gq = (q < 2) ? g0 : g1;    // row-quad-side group (C rows)

        // --- gather bases: 8 addrs once; t-steps are imm offsets ---
        int4 id0 = *(const int4*)(tf_idx + g0 * K_ + 4 * q);
        int4 id1 = *(const int4*)(tf_idx + g1 * K_ + 4 * q);
        const unsigned vb0 = (unsigned)((bh * 128 + col) * 4);
        const char* p0 = fc + (((unsigned)id0.x << 10) + vb0);
        const char* p1 = fc + (((unsigned)id0.y << 10) + vb0);
        const char* p2 = fc + (((unsigned)id0.z << 10) + vb0);
        const char* p3 = fc + (((unsigned)id0.w << 10) + vb0);
        const char* p4 = fc + (((unsigned)id1.x << 10) + vb0);
        const char* p5 = fc + (((unsigned)id1.y << 10) + vb0);
        const char* p6 = fc + (((unsigned)id1.z << 10) + vb0);
        const char* p7 = fc + (((unsigned)id1.w << 10) + vb0);

        // --- hoisted gathers: 8 tiles x 8 values (64 VGPR), deep ILP ---
        float xv[8][8];
        #pragma unroll
        for (int t = 0; t < 8; ++t) {
            xv[t][0] = *(const float*)(p0 + t * 64);
            xv[t][1] = *(const float*)(p1 + t * 64);
            xv[t][2] = *(const float*)(p2 + t * 64);
            xv[t][3] = *(const float*)(p3 + t * 64);
            xv[t][4] = *(const float*)(p4 + t * 64);
            xv[t][5] = *(const float*)(p5 + t * 64);
            xv[t][6] = *(const float*)(p6 + t * 64);
            xv[t][7] = *(const float*)(p7 + t * 64);
        }

        // --- A1: rows0-7 = LOG2E*W1_g0[w][k], rows8-15 = g1; split halves ---
        float4 w1v = *(const float4*)(W1 + ((long)ga * W_ + ra) * K_ + 4 * q);
        uint2 af;
        af.x = cvtpk_u(LOG2E * w1v.x, LOG2E * w1v.y);
        af.y = cvtpk_u(LOG2E * w1v.z, LOG2E * w1v.w);
        uint2 A1g0, A1g1;
        A1g0.x = rlt8 ? af.x : 0u;  A1g0.y = rlt8 ? af.y : 0u;
        A1g1.x = rlt8 ? 0u : af.x;  A1g1.y = rlt8 ? 0u : af.y;

        // --- AM0/AM1 block-diag: nonzero iff (col<8)==(q<2) ---
        const bool diag = (rlt8 == (q < 2));
        float4 wm0v = *(const float4*)(Wm + ((long)0 * G_ + ga) * 64 + ra * 8 + kq);
        float4 wm1v = *(const float4*)(Wm + ((long)1 * G_ + ga) * 64 + ra * 8 + kq);
        uint2 AM0, AM1;
        AM0.x = diag ? cvtpk_u(SL * wm0v.x, SL * wm0v.y) : 0u;
        AM0.y = diag ? cvtpk_u(SL * wm0v.z, SL * wm0v.w) : 0u;
        AM1.x = diag ? cvtpk_u(SL * wm1v.x, SL * wm1v.y) : 0u;
        AM1.y = diag ? cvtpk_u(SL * wm1v.z, SL * wm1v.w) : 0u;

        // --- AF: row0 = SCALE*Wf_g0 (k0-7); row8 = SCALE*Wf_g1 (k8-15) ---
        const bool fnz = (ra == 0) && diag;
        float4 wfv = *(const float4*)(Wf + (long)ga * W_ + kq);
        uint2 AF;
        AF.x = fnz ? cvtpk_u(SCALE * wfv.x, SCALE * wfv.y) : 0u;
        AF.y = fnz ? cvtpk_u(SCALE * wfv.z, SCALE * wfv.w) : 0u;

        // --- bias C-in frags (rows 4q..4q+3) ---
        float4 b1v  = *(const float4*)(b1 + (long)gq * W_ + kq);
        float4 bm0v = *(const float4*)(bm + ((long)0 * G_ + gq) * W_ + kq);
        float4 bm1v = *(const float4*)(bm + ((long)1 * G_ + gq) * W_ + kq);
        f4v bias1 = {LOG2E * b1v.x,  LOG2E * b1v.y,  LOG2E * b1v.z,  LOG2E * b1v.w};
        f4v bmf0  = {LOG2E * bm0v.x, LOG2E * bm0v.y, LOG2E * bm0v.z, LOG2E * bm0v.w};
        f4v bmf1  = {LOG2E * bm1v.x, LOG2E * bm1v.y, LOG2E * bm1v.z, LOG2E * bm1v.w};
        f4v bfin  = {0.f, 0.f, 0.f, 0.f};
        bfin[0] = ((q & 1) == 0) ? bf[gq] : 0.0f;   // rows 0 (g0) and 8 (g1)

        // --- chains processed in PAIRS, statements alternated: every
        //     mfma/selu has an adjacent independent twin ---
        #pragma unroll
        for (int t = 0; t < 8; t += 2) {
            uint2 bgA0, bgA1, bgB0, bgB1;
            bgA0.x = cvtpk_u(xv[t][0], xv[t][1]);
            bgB0.x = cvtpk_u(xv[t+1][0], xv[t+1][1]);
            bgA0.y = cvtpk_u(xv[t][2], xv[t][3]);
            bgB0.y = cvtpk_u(xv[t+1][2], xv[t+1][3]);
            bgA1.x = cvtpk_u(xv[t][4], xv[t][5]);
            bgB1.x = cvtpk_u(xv[t+1][4], xv[t+1][5]);
            bgA1.y = cvtpk_u(xv[t][6], xv[t][7]);
            bgB1.y = cvtpk_u(xv[t+1][6], xv[t+1][7]);

            f4v accA = mfma16(A1g0, bgA0, bias1);
            f4v accB = mfma16(A1g0, bgB0, bias1);
            accA = mfma16(A1g1, bgA1, accA);
            accB = mfma16(A1g1, bgB1, accB);

            uint2 bhA = selu_quad(accA);
            uint2 bhB = selu_quad(accB);
            accA = mfma16(AM0, bhA, bmf0);
            accB = mfma16(AM0, bhB, bmf0);
            bhA = selu_quad(accA);
            bhB = selu_quad(accB);
            accA = mfma16(AM1, bhA, bmf1);
            accB = mfma16(AM1, bhB, bmf1);
            bhA = selu_quad(accA);
            bhB = selu_quad(accB);
            accA = mfma16(AF, bhA, bfin);
            accB = mfma16(AF, bhB, bfin);

            // D row0 (g even) in lanes q==0, row8 (g odd) in q==2
            if (!(q & 1)) {
                smem[t * 16 + col][2 * pp + ((q >> 1) & 1)] = accA[0];
                smem[(t + 1) * 16 + col][2 * pp + ((q >> 1) & 1)] = accB[0];
            }
        }
    }

    __syncthreads();

    // epilogue: 4 threads per batch row (float4 each) -> full 64B lines
    {
        const int row = tid >> 2;           // 0..127 (local batch row)
        const int seg = tid & 3;            // 16B segment within the line
        float4 v = make_float4(smem[row][seg * 4 + 0], smem[row][seg * 4 + 1],
                               smem[row][seg * 4 + 2], smem[row][seg * 4 + 3]);
        *(float4*)(out + (long)(bh * 128 + row) * G_ + gc * 16 + seg * 4) = v;
    }
}

// ---------- fallback (no workspace): direct scalar path ----------
#define FGPB 4
__device__ __forceinline__ float selu_f(float x) {
    const float scale = 1.0507009873554805f;
    const float sa    = 1.7580993408473766f;
    float e   = __expf(x);
    float neg = fmaf(sa, e, -sa);
    return x > 0.0f ? scale * x : neg;
}
template<bool TRANSPOSED>
__global__ __launch_bounds__(256) void decoder_kernel(
    const float* __restrict__ featsrc, const int* __restrict__ tf_idx,
    const float* __restrict__ W1, const float* __restrict__ b1,
    const float* __restrict__ Wm, const float* __restrict__ bm,
    const float* __restrict__ Wf, const float* __restrict__ bf,
    float* __restrict__ out)
{
    const int b  = threadIdx.x;
    const int g0 = blockIdx.x * FGPB;
    float res[FGPB];
    #pragma unroll
    for (int gi = 0; gi < FGPB; ++gi) {
        const int g = g0 + gi;
        float xg[K_];
        #pragma unroll
        for (int k = 0; k < K_; ++k) {
            int t = tf_idx[g * K_ + k];
            xg[k] = TRANSPOSED ? featsrc[t * B_ + b] : featsrc[b * T_ + t];
        }
        float h[W_];
        #pragma unroll
        for (int w = 0; w < W_; ++w) {
            float acc = b1[g * W_ + w];
            #pragma unroll
            for (int k = 0; k < K_; ++k)
                acc = fmaf(xg[k], W1[(g * W_ + w) * K_ + k], acc);
            h[w] = selu_f(acc);
        }
        #pragma unroll
        for (int d = 0; d < D_; ++d) {
            const float* wmd = Wm + ((size_t)d * G_ + g) * (W_ * W_);
            const float* bmd = bm + ((size_t)d * G_ + g) * W_;
            float h2[W_];
            #pragma unroll
            for (int v = 0; v < W_; ++v) {
                float acc = bmd[v];
                #pragma unroll
                for (int w = 0; w < W_; ++w)
                    acc = fmaf(h[w], wmd[v * W_ + w], acc);
                h2[v] = selu_f(acc);
            }
            #pragma unroll
            for (int w = 0; w < W_; ++w) h[w] = h2[w];
        }
        float acc = bf[g];
        #pragma unroll
        for (int w = 0; w < W_; ++w)
            acc = fmaf(h[w], Wf[g * W_ + w], acc);
        res[gi] = acc;
    }
    float4* o = (float4*)(out + (size_t)b * G_ + g0);
    o[0] = make_float4(res[0], res[1], res[2], res[3]);
}

extern "C" void kernel_launch(void* const* d_in, const int* in_sizes, int n_in,
                              void* d_out, int out_size, void* d_ws, size_t ws_size,
                              hipStream_t stream) {
    const float* feat   = (const float*)d_in[0];
    const int*   tf_idx = (const int*)  d_in[1];
    const float* W1     = (const float*)d_in[2];
    const float* b1     = (const float*)d_in[3];
    const float* Wm     = (const float*)d_in[4];
    const float* bm     = (const float*)d_in[5];
    const float* Wf     = (const float*)d_in[6];
    const float* bf     = (const float*)d_in[7];
    float* out = (float*)d_out;

    const size_t featT_b = (size_t)T_ * B_ * sizeof(float);   // 1.536 MB

    if (ws_size >= featT_b) {
        float* featT = (float*)d_ws;
        hipLaunchKernelGGL(transpose_feat, dim3((T_ + 31) / 32, B_ / 32),
                           dim3(32, 8), 0, stream, feat, featT);
        hipLaunchKernelGGL(decoder_mfma, dim3(B_ / 128, G_ / 16), dim3(512), 0,
                           stream, featT, tf_idx, W1, b1, Wm, bm, Wf, bf, out);
    } else {
        hipLaunchKernelGGL((decoder_kernel<false>), dim3(G_ / FGPB), dim3(B_), 0,
                           stream, feat, tf_idx, W1, b1, Wm, bm, Wf, bf, out);
    }
}